// Round 2
// baseline (302.783 us; speedup 1.0000x reference)
//
#include <hip/hip_runtime.h>
#include <cmath>

// ---------------- problem constants ----------------
#define NLAYERS 100      // hidden layers (scan)
#define DIN     64       // input features
#define WDIM    100      // hidden width
#define NTT     4        // 4 n-tiles of 32 (128 neuron cols; bias col = 100)
#define NTW     2        // n-tiles per wave (wave w owns nt = 2w, 2w+1)
#define ROWS    32       // rows per block (ONE 32-row tile)
#define KS      7        // 7 k-steps of 16 -> K=112 (useful 101)
#define PSTR    136      // f16 h row stride (272 B, b128-aligned)
#define BUF     (ROWS * PSTR)   // one 32-row h buffer in halves

typedef _Float16 half8  __attribute__((ext_vector_type(8)));
typedef _Float16 half2v __attribute__((ext_vector_type(2)));
typedef __fp16   fp16x2 __attribute__((ext_vector_type(2)));
typedef float    f32x4  __attribute__((ext_vector_type(4)));
typedef float    f32x16 __attribute__((ext_vector_type(16)));

// ---------------- workspace layout ----------------
// wsh: [l][ks7][nt4][lane][8] — frag stride 512 halves (1024 B).
// A-frag (32x32x16, operand-swapped W^T): lane -> neuron n = nt*32+(lane&31);
// elem j -> k = ks*16 + (lane>>5)*8 + j.
//   k<100 && n<100   -> Ws[l][k][n]
//   k==100 && n<100  -> bs[l][n]      (bias row vs h col 100 == 1.0)
//   k==100 && n==100 -> 1.0           (bias col self-sustains)
#define WSH_LAYER_HALVES (KS * NTT * 64 * 8)             // 14336
#define WSH_HALVES       (NLAYERS * WSH_LAYER_HALVES)    // 1,433,600
#define W0_HALVES        (4 * NTT * 64 * 8)              // 8192 (input, K=64 = 4 ks)
#define BPAD_FLOATS      128                             // b_in padded; col 100 = 1.0
#define OFF_BPAD_B       ((WSH_HALVES + W0_HALVES) * 2)
#define OFF_WOUT_B       (OFF_BPAD_B + BPAD_FLOATS * 4)
#define WOUT_FLOATS      128

// ============================================================
// prep v2 (unchanged from r18): one block per (l,ks); coalesced row
// reads -> 8KB LDS f32 tile [16k][128n] -> coalesced half8 frag stores.
// ============================================================
__global__ __launch_bounds__(256)
void actor_prep(const float* __restrict__ Win, const float* __restrict__ bin,
                const float* __restrict__ Ws,  const float* __restrict__ bs,
                const float* __restrict__ Wout,
                _Float16* __restrict__ wsh, _Float16* __restrict__ w0sh,
                float* __restrict__ bpad, float* __restrict__ woutp) {
    __shared__ float tile[16 * 128];
    const int bid = blockIdx.x, tid = threadIdx.x;
    if (bid < NLAYERS * KS) {                       // hidden-layer weights
        const int l = bid / KS, ks = bid % KS;
#pragma unroll
        for (int e = 0; e < 8; ++e) {
            int idx = tid + 256 * e;                // coalesced: tid fastest
            int kk = idx >> 7, nn = idx & 127;
            int k = ks * 16 + kk;
            float v = 0.f;
            if (k < WDIM && nn < WDIM)        v = Ws[(l * WDIM + k) * WDIM + nn];
            else if (k == WDIM && nn < WDIM)  v = bs[l * WDIM + nn];   // bias row
            else if (k == WDIM && nn == WDIM) v = 1.0f;                // bias col alive
            tile[idx] = v;
        }
        __syncthreads();
        const int lane = tid & 63, nt = tid >> 6;
        const int g = lane >> 5, n = nt * 32 + (lane & 31);
        half8 o;
#pragma unroll
        for (int j = 0; j < 8; ++j) o[j] = (_Float16)tile[(g * 8 + j) * 128 + n];
        *(half8*)(wsh + (((l * KS + ks) * NTT + nt) << 9) + lane * 8) = o;
        return;
    }
    int b2 = bid - NLAYERS * KS;
    if (b2 < 4) {                                   // input layer (K=64)
        const int ks = b2;
#pragma unroll
        for (int e = 0; e < 8; ++e) {
            int idx = tid + 256 * e;
            int kk = idx >> 7, nn = idx & 127;
            int k = ks * 16 + kk;                   // < 64
            tile[idx] = (nn < WDIM) ? Win[k * WDIM + nn] : 0.f;
        }
        __syncthreads();
        const int lane = tid & 63, nt = tid >> 6;
        const int g = lane >> 5, n = nt * 32 + (lane & 31);
        half8 o;
#pragma unroll
        for (int j = 0; j < 8; ++j) o[j] = (_Float16)tile[(g * 8 + j) * 128 + n];
        *(half8*)(w0sh + ((ks * NTT + nt) << 9) + lane * 8) = o;
        return;
    }
    // last block: padded b_in (col 100 = 1.0 seed) + padded W_out
    if (tid < BPAD_FLOATS) {
        bpad[tid] = (tid < WDIM) ? bin[tid] : (tid == WDIM ? 1.0f : 0.f);
    } else {
        int t = tid - BPAD_FLOATS;
        if (t < WOUT_FLOATS) woutp[t] = (t < WDIM) ? Wout[t] : 0.f;
    }
}

// split fp32 -> hi/lo fp16 (layer-0 input only: keep input fidelity)
__device__ __forceinline__ void split8(const float* __restrict__ p, half8& hi, half8& lo) {
    f32x4 u0 = *(const f32x4*)p;
    f32x4 u1 = *(const f32x4*)(p + 4);
    float v[8] = {u0[0], u0[1], u0[2], u0[3], u1[0], u1[1], u1[2], u1[3]};
#pragma unroll
    for (int e = 0; e < 8; e += 2) {
        fp16x2 h = __builtin_amdgcn_cvt_pkrtz(v[e], v[e + 1]);
        float r0 = v[e]     - (float)h[0];
        float r1 = v[e + 1] - (float)h[1];
        fp16x2 l = __builtin_amdgcn_cvt_pkrtz(r0, r1);
        hi[e] = (_Float16)h[0]; hi[e + 1] = (_Float16)h[1];
        lo[e] = (_Float16)l[0]; lo[e + 1] = (_Float16)l[1];
    }
}

// epilogue one QUAD (regs 4qd..4qd+3 of a 32x32 C = 4 contiguous neurons):
// RNE f16 cvt, packed-f16 leaky, one b64 store
__device__ __forceinline__ void ep_quad(const f32x16 a, int qd, _Float16* __restrict__ d) {
    half2v p01, p23;
    p01[0] = (_Float16)a[4 * qd + 0]; p01[1] = (_Float16)a[4 * qd + 1];
    p23[0] = (_Float16)a[4 * qd + 2]; p23[1] = (_Float16)a[4 * qd + 3];
    const half2v slope = {(_Float16)0.01f, (_Float16)0.01f};
    p01 = __builtin_elementwise_max(p01, p01 * slope);
    p23 = __builtin_elementwise_max(p23, p23 * slope);
    uint2 w;
    w.x = __builtin_bit_cast(unsigned, p01);
    w.y = __builtin_bit_cast(unsigned, p23);
    *reinterpret_cast<uint2*>(d) = w;
}

// ============================================================
// Main r19: 32-ROW blocks (128 thr, 2 waves), wave owns NTW=2 n-tiles,
// grid 2048 -> exactly 8 blocks/CU, 16 waves/CU, 4/SIMD, no tail.
// Post-mortem r18 (212us): wave=1nt doubled LDS h-reads (bh is
// lane-only -> every wave re-reads full K); per-CU LDS pipe 1850->3200
// cy/layer became the floor. r17 (200us) had the right LDS traffic but
// only 2 waves/SIMD (latency slack 2.6x). This config keeps r17's
// LDS traffic (each bh read feeds 2 MFMAs; 112 b128/CU/layer) AND
// r18's occupancy. Floors: MFMA 1792, LDS ~1850 cy/CU/layer.
// Swizzle note (r18 measured): b128 row-stride-68 reads are 2-way per
// 16-lane phase with OR without the XOR swizzle (~12.6 cy/read = b128
// practical ceiling, m134); kept only for layout continuity.
// C/D layout (HW-verified m74/m101): col(batch)=lane&31,
// row(neuron)=(reg&3)+8*(reg>>2)+4*(lane>>5). h double-buffered by
// layer parity, 1 lgkm-only barrier/layer (W refills stay in flight).
// HI-ONLY f16 activations (absmax 0.094, r8-r16).
// ============================================================
__global__ __launch_bounds__(128, 4)
void actor_main(const float* __restrict__ x,
                const _Float16* __restrict__ wsh,
                const _Float16* __restrict__ w0sh,
                const float* __restrict__ bpad,
                const float* __restrict__ woutp,
                const float* __restrict__ bout,
                float* __restrict__ out) {
    __shared__ __align__(16) _Float16 hp[2 * BUF];   // 2 x 32x136 halves = 17408 B
    const int lane = threadIdx.x & 63;
    const int wid  = threadIdx.x >> 6;   // 0,1: owns nt {2w, 2w+1}
    const int g = lane >> 5, b31 = lane & 31;
    const int sw = ((b31 >> 3) & 1) << 5;            // layout swizzle (halves)
    const int rowbase = blockIdx.x * ROWS;
    const int ntb = wid * NTW;

    f32x16 acc[NTW];
    half8 wb[KS][NTW];                   // my W frags for the whole layer
    const f32x16 zero16 = {0,0,0,0, 0,0,0,0, 0,0,0,0, 0,0,0,0};

    // ---- input layer (K=64 = 4 k-steps of 16) ----
    {
        half8 w0[4][NTW];
#pragma unroll
        for (int ks = 0; ks < 4; ++ks)
#pragma unroll
            for (int ntl = 0; ntl < NTW; ++ntl)
                w0[ks][ntl] = *(const half8*)(w0sh + (ks * NTT + ntb + ntl) * 512 + lane * 8);
#pragma unroll
        for (int ntl = 0; ntl < NTW; ++ntl)
#pragma unroll
            for (int qd = 0; qd < 4; ++qd) {
                f32x4 tq = *(const f32x4*)(bpad + (ntb + ntl) * 32 + 8 * qd + 4 * g);
#pragma unroll
                for (int r = 0; r < 4; ++r) acc[ntl][4 * qd + r] = tq[r];
            }
        const float* xr = x + (rowbase + b31) * DIN;
#pragma unroll
        for (int ks = 0; ks < 4; ++ks) {
            half8 xhi, xlo;
            split8(xr + ks * 16 + g * 8, xhi, xlo);
#pragma unroll
            for (int ntl = 0; ntl < NTW; ++ntl) {
                acc[ntl] = __builtin_amdgcn_mfma_f32_32x32x16_f16(w0[ks][ntl], xhi, acc[ntl], 0, 0, 0);
                acc[ntl] = __builtin_amdgcn_mfma_f32_32x32x16_f16(w0[ks][ntl], xlo, acc[ntl], 0, 0, 0);
            }
        }
    }
    // epi0 -> buffer 0 (swizzled); prefetch W(0)
#pragma unroll
    for (int ntl = 0; ntl < NTW; ++ntl) {
        _Float16* d = hp + b31 * PSTR + (((ntb + ntl) * 32 + 4 * g) ^ sw);
#pragma unroll
        for (int qd = 0; qd < 4; ++qd) ep_quad(acc[ntl], qd, d + 8 * qd);
    }
#pragma unroll
    for (int ks = 0; ks < KS; ++ks)
#pragma unroll
        for (int ntl = 0; ntl < NTW; ++ntl)
            wb[ks][ntl] = *(const half8*)(wsh + (ks * NTT + ntb + ntl) * 512 + lane * 8);
    asm volatile("s_waitcnt lgkmcnt(0)\n\ts_barrier" ::: "memory");

    // ---------------- 100 hidden layers ----------------
    // layer l: reads buf[l&1] (h of l-1), writes buf[(l+1)&1]
#pragma unroll 1
    for (int l = 0; l < NLAYERS; ++l) {
        const _Float16* rb = hp + (l & 1) * BUF;
        _Float16* wbf = hp + ((l + 1) & 1) * BUF;
        const _Float16* wn = wsh + (l < NLAYERS - 1 ? l + 1 : l) * WSH_LAYER_HALVES;
        half8 bh[KS];

#pragma unroll
        for (int ks = 0; ks < KS; ++ks)
            bh[ks] = *(const half8*)(rb + b31 * PSTR + ((ks * 16 + g * 8) ^ sw));
        // 14 MFMAs as 2 interleaved chains; wb[ks] refilled with W(L+1)
        // right after its (only) use — loads stay in flight across the
        // lgkm-only barrier (T4), compiler inserts counted vmcnt at use.
#pragma unroll
        for (int ks = 0; ks < KS; ++ks) {
            acc[0] = __builtin_amdgcn_mfma_f32_32x32x16_f16(
                wb[ks][0], bh[ks], (ks == 0 ? zero16 : acc[0]), 0, 0, 0);
            acc[1] = __builtin_amdgcn_mfma_f32_32x32x16_f16(
                wb[ks][1], bh[ks], (ks == 0 ? zero16 : acc[1]), 0, 0, 0);
            wb[ks][0] = *(const half8*)(wn + (ks * NTT + ntb + 0) * 512 + lane * 8);
            wb[ks][1] = *(const half8*)(wn + (ks * NTT + ntb + 1) * 512 + lane * 8);
        }
        // epi: 8 quads (2 nt x 4), then lgkm-only layer barrier
        {
            _Float16* d0 = wbf + b31 * PSTR + (((ntb + 0) * 32 + 4 * g) ^ sw);
            _Float16* d1 = wbf + b31 * PSTR + (((ntb + 1) * 32 + 4 * g) ^ sw);
#pragma unroll
            for (int qd = 0; qd < 4; ++qd) {
                ep_quad(acc[0], qd, d0 + 8 * qd);
                ep_quad(acc[1], qd, d1 + 8 * qd);
            }
        }
        asm volatile("s_waitcnt lgkmcnt(0)\n\ts_barrier" ::: "memory");
    }
    // acc[ntl] = pre-activation of layer 99 for my neurons (in regs)

    // ---------------- heads: leaky + dot(W_out), combine via LDS ----------------
    float s = 0.f;
#pragma unroll
    for (int ntl = 0; ntl < NTW; ++ntl)
#pragma unroll
        for (int qd = 0; qd < 4; ++qd) {
            f32x4 w4 = *(const f32x4*)(woutp + (ntb + ntl) * 32 + 8 * qd + 4 * g);
#pragma unroll
            for (int r = 0; r < 4; ++r) {
                float a = acc[ntl][4 * qd + r];
                float v = fmaxf(a, 0.01f * a);
                s += v * w4[r];
            }
        }
    s += __shfl_xor(s, 32);              // combine the two k-groups (same batch col)
    float* red = (float*)hp;             // scratch (final barrier already passed)
    if (lane < 32) red[wid * 32 + b31] = s;
    __syncthreads();
    if (threadIdx.x < 32) {
        const int r = threadIdx.x;
        float tot = red[r] + red[32 + r] + bout[0];
        out[rowbase + r] = tanhf(tot) * 4.5f + 5.5f;   // (tanh+1)/2*9 + 1
    }
}

extern "C" void kernel_launch(void* const* d_in, const int* in_sizes, int n_in,
                              void* d_out, int out_size, void* d_ws, size_t ws_size,
                              hipStream_t stream) {
    const float* x    = (const float*)d_in[0];
    const float* Win  = (const float*)d_in[1];
    const float* bin  = (const float*)d_in[2];
    const float* Ws   = (const float*)d_in[3];
    const float* bs   = (const float*)d_in[4];
    const float* Wout = (const float*)d_in[5];
    const float* bout = (const float*)d_in[6];
    float* out = (float*)d_out;

    char* ws = (char*)d_ws;
    _Float16* wsh  = (_Float16*)ws;
    _Float16* w0sh = wsh + WSH_HALVES;
    float* bpad  = (float*)(ws + OFF_BPAD_B);
    float* woutp = (float*)(ws + OFF_WOUT_B);

    hipLaunchKernelGGL(actor_prep, dim3(NLAYERS * KS + 4 + 1), dim3(256), 0, stream,
                       Win, bin, Ws, bs, Wout, wsh, w0sh, bpad, woutp);

    const int nrows = in_sizes[0] / DIN;   // 65536
    hipLaunchKernelGGL(actor_main, dim3(nrows / ROWS), dim3(128), 0, stream,
                       x, wsh, w0sh, bpad, woutp, bout, out);
}

// Round 3
// 299.699 us; speedup vs baseline: 1.0103x; 1.0103x over previous
//
#include <hip/hip_runtime.h>
#include <cmath>

// ---------------- problem constants ----------------
#define NLAYERS 100      // hidden layers (scan)
#define DIN     64       // input features
#define WDIM    100      // hidden width
#define NTT     4        // 4 n-tiles of 32 (128 neuron cols; bias col = 100)
#define ROWS    32       // rows per block = rows per WAVE
#define KS      7        // 7 k-steps of 16 -> K=112 (useful 101)
#define PSTR    136      // f16 h row stride (272 B, b128-aligned)
#define BUF     (ROWS * PSTR)   // wave-private h buffer: 4352 halves = 8704 B

typedef _Float16 half8  __attribute__((ext_vector_type(8)));
typedef _Float16 half2v __attribute__((ext_vector_type(2)));
typedef __fp16   fp16x2 __attribute__((ext_vector_type(2)));
typedef float    f32x4  __attribute__((ext_vector_type(4)));
typedef float    f32x16 __attribute__((ext_vector_type(16)));

// ---------------- workspace layout ----------------
// wsh: [l][ks7][nt4][lane][8] — frag stride 512 halves (1024 B).
// A-frag (32x32x16, operand-swapped W^T): lane -> neuron n = nt*32+(lane&31);
// elem j -> k = ks*16 + (lane>>5)*8 + j.
//   k<100 && n<100   -> Ws[l][k][n]
//   k==100 && n<100  -> bs[l][n]      (bias row vs h col 100 == 1.0)
//   k==100 && n==100 -> 1.0           (bias col self-sustains)
#define WSH_LAYER_HALVES (KS * NTT * 64 * 8)             // 14336
#define WSH_HALVES       (NLAYERS * WSH_LAYER_HALVES)    // 1,433,600
#define W0_HALVES        (4 * NTT * 64 * 8)              // 8192 (input, K=64 = 4 ks)
#define BPAD_FLOATS      128                             // b_in padded; col 100 = 1.0
#define OFF_BPAD_B       ((WSH_HALVES + W0_HALVES) * 2)
#define OFF_WOUT_B       (OFF_BPAD_B + BPAD_FLOATS * 4)
#define WOUT_FLOATS      128

// ============================================================
// prep v2 (unchanged): one block per (l,ks); coalesced row reads ->
// 8KB LDS f32 tile [16k][128n] -> coalesced half8 frag stores.
// ============================================================
__global__ __launch_bounds__(256)
void actor_prep(const float* __restrict__ Win, const float* __restrict__ bin,
                const float* __restrict__ Ws,  const float* __restrict__ bs,
                const float* __restrict__ Wout,
                _Float16* __restrict__ wsh, _Float16* __restrict__ w0sh,
                float* __restrict__ bpad, float* __restrict__ woutp) {
    __shared__ float tile[16 * 128];
    const int bid = blockIdx.x, tid = threadIdx.x;
    if (bid < NLAYERS * KS) {                       // hidden-layer weights
        const int l = bid / KS, ks = bid % KS;
#pragma unroll
        for (int e = 0; e < 8; ++e) {
            int idx = tid + 256 * e;                // coalesced: tid fastest
            int kk = idx >> 7, nn = idx & 127;
            int k = ks * 16 + kk;
            float v = 0.f;
            if (k < WDIM && nn < WDIM)        v = Ws[(l * WDIM + k) * WDIM + nn];
            else if (k == WDIM && nn < WDIM)  v = bs[l * WDIM + nn];   // bias row
            else if (k == WDIM && nn == WDIM) v = 1.0f;                // bias col alive
            tile[idx] = v;
        }
        __syncthreads();
        const int lane = tid & 63, nt = tid >> 6;
        const int g = lane >> 5, n = nt * 32 + (lane & 31);
        half8 o;
#pragma unroll
        for (int j = 0; j < 8; ++j) o[j] = (_Float16)tile[(g * 8 + j) * 128 + n];
        *(half8*)(wsh + (((l * KS + ks) * NTT + nt) << 9) + lane * 8) = o;
        return;
    }
    int b2 = bid - NLAYERS * KS;
    if (b2 < 4) {                                   // input layer (K=64)
        const int ks = b2;
#pragma unroll
        for (int e = 0; e < 8; ++e) {
            int idx = tid + 256 * e;
            int kk = idx >> 7, nn = idx & 127;
            int k = ks * 16 + kk;                   // < 64
            tile[idx] = (nn < WDIM) ? Win[k * WDIM + nn] : 0.f;
        }
        __syncthreads();
        const int lane = tid & 63, nt = tid >> 6;
        const int g = lane >> 5, n = nt * 32 + (lane & 31);
        half8 o;
#pragma unroll
        for (int j = 0; j < 8; ++j) o[j] = (_Float16)tile[(g * 8 + j) * 128 + n];
        *(half8*)(w0sh + ((ks * NTT + nt) << 9) + lane * 8) = o;
        return;
    }
    // last block: padded b_in (col 100 = 1.0 seed) + padded W_out
    if (tid < BPAD_FLOATS) {
        bpad[tid] = (tid < WDIM) ? bin[tid] : (tid == WDIM ? 1.0f : 0.f);
    } else {
        int t = tid - BPAD_FLOATS;
        if (t < WOUT_FLOATS) woutp[t] = (t < WDIM) ? Wout[t] : 0.f;
    }
}

// split fp32 -> hi/lo fp16 (layer-0 input only: keep input fidelity)
__device__ __forceinline__ void split8(const float* __restrict__ p, half8& hi, half8& lo) {
    f32x4 u0 = *(const f32x4*)p;
    f32x4 u1 = *(const f32x4*)(p + 4);
    float v[8] = {u0[0], u0[1], u0[2], u0[3], u1[0], u1[1], u1[2], u1[3]};
#pragma unroll
    for (int e = 0; e < 8; e += 2) {
        fp16x2 h = __builtin_amdgcn_cvt_pkrtz(v[e], v[e + 1]);
        float r0 = v[e]     - (float)h[0];
        float r1 = v[e + 1] - (float)h[1];
        fp16x2 l = __builtin_amdgcn_cvt_pkrtz(r0, r1);
        hi[e] = (_Float16)h[0]; hi[e + 1] = (_Float16)h[1];
        lo[e] = (_Float16)l[0]; lo[e + 1] = (_Float16)l[1];
    }
}

// epilogue one QUAD (regs 4qd..4qd+3 of a 32x32 C = 4 contiguous neurons):
// RNE f16 cvt, packed-f16 leaky, one b64 store
__device__ __forceinline__ void ep_quad(const f32x16 a, int qd, _Float16* __restrict__ d) {
    half2v p01, p23;
    p01[0] = (_Float16)a[4 * qd + 0]; p01[1] = (_Float16)a[4 * qd + 1];
    p23[0] = (_Float16)a[4 * qd + 2]; p23[1] = (_Float16)a[4 * qd + 3];
    const half2v slope = {(_Float16)0.01f, (_Float16)0.01f};
    p01 = __builtin_elementwise_max(p01, p01 * slope);
    p23 = __builtin_elementwise_max(p23, p23 * slope);
    uint2 w;
    w.x = __builtin_bit_cast(unsigned, p01);
    w.y = __builtin_bit_cast(unsigned, p23);
    *reinterpret_cast<uint2*>(d) = w;
}

// ============================================================
// Main r20: ONE WAVE PER BLOCK (64 thr), wave owns 32 rows x ALL 4
// n-tiles -> ZERO barriers, zero inter-wave dependencies.
// Post-mortem r18/r19: any split of a 32-row group across waves forces
// either 2x LDS reads (r18) or 2x VMEM + broken refill (r19: VGPR=56
// proved the compiler sank the W refills past the barrier). The barrier
// convoy held r17 at 4600cy/layer vs ~2000cy pipe floors (all pipes
// <50% busy). Barrier-free structure:
//  - h is wave-private: epi writes + next-layer bh reads in one 8.7KB
//    LDS buffer (DS in-order per wave; no sync, single buffer safe:
//    all 7 bh reads land in regs before any epi write issues).
//  - 7 ds_read_b128/layer (each feeds 4 MFMAs) — HALF of r17's reads.
//  - W refill keeps full-layer lookahead: wb[7][4]=112 VGPR, refilled
//    dead-after-use, ~2000cy to land -> latency-immune, throughput-only.
//  - acc[4]=64 VGPR -> 4 independent MFMA chains.
//  - head: wave owns all 128 neurons -> shfl_xor(32) only, no LDS redn.
// Budget/CU-layer (8 waves = 2/SIMD, grid 2048): MFMA 1792cy,
// LDS ~900cy, VMEM 224KB @ ~90B/cy ~2500cy (designed bottleneck; wsh
// 2.87MB is L2-resident per XCD). VGPR ~230 <= 256 (launch_bounds 64,2).
// C/D layout (HW-verified m74/m101): col(batch)=lane&31,
// row(neuron)=(reg&3)+8*(reg>>2)+4*(lane>>5).
// HI-ONLY f16 activations, bias via k=100 row x h[100]=1 (absmax
// 0.09375, unchanged math from r17).
// ============================================================
__global__ __launch_bounds__(64, 2)
void actor_main(const float* __restrict__ x,
                const _Float16* __restrict__ wsh,
                const _Float16* __restrict__ w0sh,
                const float* __restrict__ bpad,
                const float* __restrict__ woutp,
                const float* __restrict__ bout,
                float* __restrict__ out) {
    __shared__ __align__(16) _Float16 hp[BUF];   // wave-private h (8704 B)
    const int lane = threadIdx.x;                // 0..63 (one wave)
    const int g = lane >> 5, b31 = lane & 31;
    const int rowbase = blockIdx.x * ROWS;

    f32x16 acc[NTT];                 // 64 VGPR, 4 independent chains
    half8 wb[KS][NTT];               // 112 VGPR: full layer W, refill-after-use
    const f32x16 zero16 = {0,0,0,0, 0,0,0,0, 0,0,0,0, 0,0,0,0};

    // ---- input layer (K=64 = 4 k-steps of 16) ----
    {
        half8 w0[4][NTT];
#pragma unroll
        for (int ks = 0; ks < 4; ++ks)
#pragma unroll
            for (int nt = 0; nt < NTT; ++nt)
                w0[ks][nt] = *(const half8*)(w0sh + (ks * NTT + nt) * 512 + lane * 8);
#pragma unroll
        for (int nt = 0; nt < NTT; ++nt)
#pragma unroll
            for (int qd = 0; qd < 4; ++qd) {
                f32x4 tq = *(const f32x4*)(bpad + nt * 32 + 8 * qd + 4 * g);
#pragma unroll
                for (int r = 0; r < 4; ++r) acc[nt][4 * qd + r] = tq[r];
            }
        const float* xr = x + (rowbase + b31) * DIN;
#pragma unroll
        for (int ks = 0; ks < 4; ++ks) {
            half8 xhi, xlo;
            split8(xr + ks * 16 + g * 8, xhi, xlo);
#pragma unroll
            for (int nt = 0; nt < NTT; ++nt) {
                acc[nt] = __builtin_amdgcn_mfma_f32_32x32x16_f16(w0[ks][nt], xhi, acc[nt], 0, 0, 0);
                acc[nt] = __builtin_amdgcn_mfma_f32_32x32x16_f16(w0[ks][nt], xlo, acc[nt], 0, 0, 0);
            }
        }
    }
    // epi0 -> h buffer; then load W(0)
#pragma unroll
    for (int nt = 0; nt < NTT; ++nt) {
        _Float16* d = hp + b31 * PSTR + nt * 32 + 4 * g;
#pragma unroll
        for (int qd = 0; qd < 4; ++qd) ep_quad(acc[nt], qd, d + 8 * qd);
    }
#pragma unroll
    for (int ks = 0; ks < KS; ++ks)
#pragma unroll
        for (int nt = 0; nt < NTT; ++nt)
            wb[ks][nt] = *(const half8*)(wsh + (ks * NTT + nt) * 512 + lane * 8);

    // ---------------- 100 hidden layers, NO barriers ----------------
#pragma unroll 1
    for (int l = 0; l < NLAYERS; ++l) {
        const _Float16* wn = wsh + (l < NLAYERS - 1 ? l + 1 : l) * WSH_LAYER_HALVES;
        half8 bh[KS];
        // bh reads wait (lgkm) on prev layer's epi writes — wave-private,
        // DS in-order; compiler fine-counts lgkmcnt per MFMA.
#pragma unroll
        for (int ks = 0; ks < KS; ++ks)
            bh[ks] = *(const half8*)(hp + b31 * PSTR + ks * 16 + g * 8);
#pragma unroll
        for (int ks = 0; ks < KS; ++ks) {
            acc[0] = __builtin_amdgcn_mfma_f32_32x32x16_f16(
                wb[ks][0], bh[ks], (ks == 0 ? zero16 : acc[0]), 0, 0, 0);
            acc[1] = __builtin_amdgcn_mfma_f32_32x32x16_f16(
                wb[ks][1], bh[ks], (ks == 0 ? zero16 : acc[1]), 0, 0, 0);
            acc[2] = __builtin_amdgcn_mfma_f32_32x32x16_f16(
                wb[ks][2], bh[ks], (ks == 0 ? zero16 : acc[2]), 0, 0, 0);
            acc[3] = __builtin_amdgcn_mfma_f32_32x32x16_f16(
                wb[ks][3], bh[ks], (ks == 0 ? zero16 : acc[3]), 0, 0, 0);
            // wb[ks] dead: refill with W(l+1)[ks] — full layer to land
#pragma unroll
            for (int nt = 0; nt < NTT; ++nt)
                wb[ks][nt] = *(const half8*)(wn + (ks * NTT + nt) * 512 + lane * 8);
        }
        // epi: 16 quads (4 nt x 4) back into the same private buffer
#pragma unroll
        for (int nt = 0; nt < NTT; ++nt) {
            _Float16* d = hp + b31 * PSTR + nt * 32 + 4 * g;
#pragma unroll
            for (int qd = 0; qd < 4; ++qd) ep_quad(acc[nt], qd, d + 8 * qd);
        }
    }
    // acc[nt] = pre-activation of layer 99 for ALL 128 neurons of my rows

    // ---------------- head: leaky + dot(W_out), wave-local ----------------
    float s = 0.f;
#pragma unroll
    for (int nt = 0; nt < NTT; ++nt)
#pragma unroll
        for (int qd = 0; qd < 4; ++qd) {
            f32x4 w4 = *(const f32x4*)(woutp + nt * 32 + 8 * qd + 4 * g);
#pragma unroll
            for (int r = 0; r < 4; ++r) {
                float a = acc[nt][4 * qd + r];
                float v = fmaxf(a, 0.01f * a);
                s += v * w4[r];
            }
        }
    s += __shfl_xor(s, 32);              // combine the two k-groups (same batch row)
    if (lane < 32) {
        float tot = s + bout[0];
        out[rowbase + b31] = tanhf(tot) * 4.5f + 5.5f;   // (tanh+1)/2*9 + 1
    }
}

extern "C" void kernel_launch(void* const* d_in, const int* in_sizes, int n_in,
                              void* d_out, int out_size, void* d_ws, size_t ws_size,
                              hipStream_t stream) {
    const float* x    = (const float*)d_in[0];
    const float* Win  = (const float*)d_in[1];
    const float* bin  = (const float*)d_in[2];
    const float* Ws   = (const float*)d_in[3];
    const float* bs   = (const float*)d_in[4];
    const float* Wout = (const float*)d_in[5];
    const float* bout = (const float*)d_in[6];
    float* out = (float*)d_out;

    char* ws = (char*)d_ws;
    _Float16* wsh  = (_Float16*)ws;
    _Float16* w0sh = wsh + WSH_HALVES;
    float* bpad  = (float*)(ws + OFF_BPAD_B);
    float* woutp = (float*)(ws + OFF_WOUT_B);

    hipLaunchKernelGGL(actor_prep, dim3(NLAYERS * KS + 4 + 1), dim3(256), 0, stream,
                       Win, bin, Ws, bs, Wout, wsh, w0sh, bpad, woutp);

    const int nrows = in_sizes[0] / DIN;   // 65536
    hipLaunchKernelGGL(actor_main, dim3(nrows / ROWS), dim3(64), 0, stream,
                       x, wsh, w0sh, bpad, woutp, bout, out);
}

// Round 4
// 256.323 us; speedup vs baseline: 1.1813x; 1.1692x over previous
//
#include <hip/hip_runtime.h>
#include <cmath>

// ---------------- problem constants ----------------
#define NLAYERS 100      // hidden layers (scan)
#define DIN     64       // input features
#define WDIM    100      // hidden width
#define NTT     4        // 4 n-tiles of 32 (128 neuron cols; bias col = 100)
#define RT      2        // two 32-row tiles -> 64 rows per wave
#define ROWS    64       // rows per block (= per wave; 1-wave blocks)
#define KS      7        // 7 k-steps of 16 -> K=112 (useful 101)

typedef _Float16 half8  __attribute__((ext_vector_type(8)));
typedef _Float16 half2v __attribute__((ext_vector_type(2)));
typedef __fp16   fp16x2 __attribute__((ext_vector_type(2)));
typedef float    f32x4  __attribute__((ext_vector_type(4)));
typedef float    f32x16 __attribute__((ext_vector_type(16)));
typedef unsigned uint4v __attribute__((ext_vector_type(4)));

// ---------------- workspace layout ----------------
// wsh: [l][ks7][nt4][lane][8] — frag stride 512 halves (1024 B).
// A-frag (32x32x16, operand-swapped W^T): lane -> neuron n = nt*32+(lane&31);
// elem j -> k = ks*16 + (lane>>5)*8 + j.
//   k<100 && n<100   -> Ws[l][k][n]
//   k==100 && n<100  -> bs[l][n]      (bias row vs h col 100 == 1.0)
//   k==100 && n==100 -> 1.0           (bias col self-sustains)
#define WSH_LAYER_HALVES (KS * NTT * 64 * 8)             // 14336
#define WSH_HALVES       (NLAYERS * WSH_LAYER_HALVES)    // 1,433,600
#define W0_HALVES        (4 * NTT * 64 * 8)              // 8192 (input, K=64 = 4 ks)
#define BPAD_FLOATS      128                             // b_in padded; col 100 = 1.0
#define OFF_BPAD_B       ((WSH_HALVES + W0_HALVES) * 2)
#define OFF_WOUT_B       (OFF_BPAD_B + BPAD_FLOATS * 4)
#define WOUT_FLOATS      128

// ============================================================
// prep v2 (unchanged): one block per (l,ks); coalesced row reads ->
// 8KB LDS f32 tile [16k][128n] -> coalesced half8 frag stores.
// ============================================================
__global__ __launch_bounds__(256)
void actor_prep(const float* __restrict__ Win, const float* __restrict__ bin,
                const float* __restrict__ Ws,  const float* __restrict__ bs,
                const float* __restrict__ Wout,
                _Float16* __restrict__ wsh, _Float16* __restrict__ w0sh,
                float* __restrict__ bpad, float* __restrict__ woutp) {
    __shared__ float tile[16 * 128];
    const int bid = blockIdx.x, tid = threadIdx.x;
    if (bid < NLAYERS * KS) {                       // hidden-layer weights
        const int l = bid / KS, ks = bid % KS;
#pragma unroll
        for (int e = 0; e < 8; ++e) {
            int idx = tid + 256 * e;                // coalesced: tid fastest
            int kk = idx >> 7, nn = idx & 127;
            int k = ks * 16 + kk;
            float v = 0.f;
            if (k < WDIM && nn < WDIM)        v = Ws[(l * WDIM + k) * WDIM + nn];
            else if (k == WDIM && nn < WDIM)  v = bs[l * WDIM + nn];   // bias row
            else if (k == WDIM && nn == WDIM) v = 1.0f;                // bias col alive
            tile[idx] = v;
        }
        __syncthreads();
        const int lane = tid & 63, nt = tid >> 6;
        const int g = lane >> 5, n = nt * 32 + (lane & 31);
        half8 o;
#pragma unroll
        for (int j = 0; j < 8; ++j) o[j] = (_Float16)tile[(g * 8 + j) * 128 + n];
        *(half8*)(wsh + (((l * KS + ks) * NTT + nt) << 9) + lane * 8) = o;
        return;
    }
    int b2 = bid - NLAYERS * KS;
    if (b2 < 4) {                                   // input layer (K=64)
        const int ks = b2;
#pragma unroll
        for (int e = 0; e < 8; ++e) {
            int idx = tid + 256 * e;
            int kk = idx >> 7, nn = idx & 127;
            int k = ks * 16 + kk;                   // < 64
            tile[idx] = (nn < WDIM) ? Win[k * WDIM + nn] : 0.f;
        }
        __syncthreads();
        const int lane = tid & 63, nt = tid >> 6;
        const int g = lane >> 5, n = nt * 32 + (lane & 31);
        half8 o;
#pragma unroll
        for (int j = 0; j < 8; ++j) o[j] = (_Float16)tile[(g * 8 + j) * 128 + n];
        *(half8*)(w0sh + ((ks * NTT + nt) << 9) + lane * 8) = o;
        return;
    }
    // last block: padded b_in (col 100 = 1.0 seed) + padded W_out
    if (tid < BPAD_FLOATS) {
        bpad[tid] = (tid < WDIM) ? bin[tid] : (tid == WDIM ? 1.0f : 0.f);
    } else {
        int t = tid - BPAD_FLOATS;
        if (t < WOUT_FLOATS) woutp[t] = (t < WDIM) ? Wout[t] : 0.f;
    }
}

// split fp32 -> hi/lo fp16 (layer-0 input only: keep input fidelity)
__device__ __forceinline__ void split8(const float* __restrict__ p, half8& hi, half8& lo) {
    f32x4 u0 = *(const f32x4*)p;
    f32x4 u1 = *(const f32x4*)(p + 4);
    float v[8] = {u0[0], u0[1], u0[2], u0[3], u1[0], u1[1], u1[2], u1[3]};
#pragma unroll
    for (int e = 0; e < 8; e += 2) {
        fp16x2 h = __builtin_amdgcn_cvt_pkrtz(v[e], v[e + 1]);
        float r0 = v[e]     - (float)h[0];
        float r1 = v[e + 1] - (float)h[1];
        fp16x2 l = __builtin_amdgcn_cvt_pkrtz(r0, r1);
        hi[e] = (_Float16)h[0]; hi[e + 1] = (_Float16)h[1];
        lo[e] = (_Float16)l[0]; lo[e + 1] = (_Float16)l[1];
    }
}

// RNE f16 cast pair + packed-f16 leaky -> one dword (same ops/precision
// as old ep_quad: (_Float16) scalar cast = RNE, then max(p, 0.01p) in f16)
__device__ __forceinline__ unsigned pack2(float a, float b) {
    half2v p; p[0] = (_Float16)a; p[1] = (_Float16)b;
    const half2v slope = {(_Float16)0.01f, (_Float16)0.01f};
    p = __builtin_elementwise_max(p, p * slope);
    return __builtin_bit_cast(unsigned, p);
}

// ============================================================
// Main r21: h handoff ENTIRELY IN REGISTERS — zero LDS, zero barriers.
// Post-mortem r17-r20: all variants wall at 200-240us vs a 19us MFMA
// floor; the limit is the serial per-layer critical path (LDS epi->bh
// round-trip ~600cy + W-refill latency exposed by compiler load-sinking
// [r19/r20: VGPR 56/128 << design]) at 1-2 waves/SIMD.
// Fix:
//  - C/D layout (col=b31, row=(reg&3)+8*(reg>>2)+4g; m74/m101) vs the
//    next layer's B-frag (lane b31 holds k=ks*16+g*8+j) differ only by
//    a lane-half exchange: elem j 0..3 comes from lane b31, j 4..7 from
//    lane b31+32, at regs r0=8*(ks&1)+(j&3)(+4*g_me via which pack).
//    So: pack_lo=f16leaky(regs r0+0..3), pack_hi=(+4..7) — then ONE
//    v_permlane32_swap_b32 per dword pair routes both halves:
//      lo' = [own lo | partner hi], hi' = [partner lo | own hi]
//    bh[ks] = {lo0',lo1',hi0',hi1'}. Bit-identical h to the old LDS
//    path (same RNE cast + f16 leaky) -> absmax unchanged.
//  - Wave = 64 rows x all 4 nt (RT=2): 1024 one-wave blocks = 4/CU =
//    1/SIMD; launch_bounds(64,1) opens the 512-VGPR budget so acc 128
//    + wb 112 (full-layer W lookahead) + bh 56 can ALL stay live.
//    asm keep-alive anchor on wb at end of layer forbids load-sinking.
//  - W traffic: 112 KB/CU-layer, same 28KB stream for the CU's 4 waves
//    (L1-broadcast); wsh 2.87MB fits each XCD L2.
// Per-layer wave cost: 56 MFMA (448cy) + ~350 VALU pack (~700cy issue,
// overlaps MFMA pipe) + 28 prefetch loads (issued ~1 layer ahead).
// ============================================================
__global__ __launch_bounds__(64, 1)
void actor_main(const float* __restrict__ x,
                const _Float16* __restrict__ wsh,
                const _Float16* __restrict__ w0sh,
                const float* __restrict__ bpad,
                const float* __restrict__ woutp,
                const float* __restrict__ bout,
                float* __restrict__ out) {
    const int lane = threadIdx.x;                // 0..63 (one wave)
    const int g = lane >> 5, b31 = lane & 31;
    const int rowbase = blockIdx.x * ROWS;

    f32x16 acc[RT][NTT];             // 128 VGPR: 8 independent MFMA chains
    half8 wb[KS][NTT];               // 112 VGPR: full-layer W, refill-after-use
    half8 bh[RT][KS];                //  56 VGPR: B-frags (next-layer input)
    const f32x16 zero16 = {0,0,0,0, 0,0,0,0, 0,0,0,0, 0,0,0,0};

    // ---- input layer (K=64 = 4 k-steps of 16), x hi/lo f16 split ----
    {
        half8 w0[4][NTT];
#pragma unroll
        for (int ks = 0; ks < 4; ++ks)
#pragma unroll
            for (int nt = 0; nt < NTT; ++nt)
                w0[ks][nt] = *(const half8*)(w0sh + (ks * NTT + nt) * 512 + lane * 8);
#pragma unroll
        for (int rt = 0; rt < RT; ++rt)
#pragma unroll
            for (int nt = 0; nt < NTT; ++nt)
#pragma unroll
                for (int qd = 0; qd < 4; ++qd) {
                    f32x4 tq = *(const f32x4*)(bpad + nt * 32 + 8 * qd + 4 * g);
#pragma unroll
                    for (int r = 0; r < 4; ++r) acc[rt][nt][4 * qd + r] = tq[r];
                }
#pragma unroll
        for (int rt = 0; rt < RT; ++rt) {
            const float* xr = x + (rowbase + rt * 32 + b31) * DIN;
#pragma unroll
            for (int ks = 0; ks < 4; ++ks) {
                half8 xhi, xlo;
                split8(xr + ks * 16 + g * 8, xhi, xlo);
#pragma unroll
                for (int nt = 0; nt < NTT; ++nt) {
                    acc[rt][nt] = __builtin_amdgcn_mfma_f32_32x32x16_f16(w0[ks][nt], xhi, acc[rt][nt], 0, 0, 0);
                    acc[rt][nt] = __builtin_amdgcn_mfma_f32_32x32x16_f16(w0[ks][nt], xlo, acc[rt][nt], 0, 0, 0);
                }
            }
        }
    }
    // build bh (h0) in regs; load W(0)
#pragma unroll
    for (int rt = 0; rt < RT; ++rt)
#pragma unroll
        for (int ks = 0; ks < KS; ++ks) {
            const int r0 = 8 * (ks & 1);
            const f32x16 a = acc[rt][ks >> 1];
            unsigned lo0 = pack2(a[r0 + 0], a[r0 + 1]);
            unsigned lo1 = pack2(a[r0 + 2], a[r0 + 3]);
            unsigned hi0 = pack2(a[r0 + 4], a[r0 + 5]);
            unsigned hi1 = pack2(a[r0 + 6], a[r0 + 7]);
            asm volatile("v_permlane32_swap_b32 %0, %1" : "+v"(lo0), "+v"(hi0));
            asm volatile("v_permlane32_swap_b32 %0, %1" : "+v"(lo1), "+v"(hi1));
            uint4v u = {lo0, lo1, hi0, hi1};
            bh[rt][ks] = __builtin_bit_cast(half8, u);
        }
#pragma unroll
    for (int ks = 0; ks < KS; ++ks)
#pragma unroll
        for (int nt = 0; nt < NTT; ++nt)
            wb[ks][nt] = *(const half8*)(wsh + (ks * NTT + nt) * 512 + lane * 8);

    // ---------------- 100 hidden layers: no LDS, no barriers ----------------
#pragma unroll 1
    for (int l = 0; l < NLAYERS; ++l) {
        const _Float16* wn = wsh + (l < NLAYERS - 1 ? l + 1 : l) * WSH_LAYER_HALVES;
        // MFMA phase: 8 independent chains; refill wb[ks] (dead after its
        // 8 MFMAs) with W(l+1) — issued here, anchored live below.
#pragma unroll
        for (int ks = 0; ks < KS; ++ks) {
#pragma unroll
            for (int rt = 0; rt < RT; ++rt)
#pragma unroll
                for (int nt = 0; nt < NTT; ++nt)
                    acc[rt][nt] = __builtin_amdgcn_mfma_f32_32x32x16_f16(
                        wb[ks][nt], bh[rt][ks], (ks == 0 ? zero16 : acc[rt][nt]), 0, 0, 0);
#pragma unroll
            for (int nt = 0; nt < NTT; ++nt)
                wb[ks][nt] = *(const half8*)(wn + (ks * NTT + nt) * 512 + lane * 8);
        }
        if (l < NLAYERS - 1) {
            // pack acc -> bh (next layer's input), all in regs
#pragma unroll
            for (int rt = 0; rt < RT; ++rt)
#pragma unroll
                for (int ks = 0; ks < KS; ++ks) {
                    const int r0 = 8 * (ks & 1);
                    const f32x16 a = acc[rt][ks >> 1];
                    unsigned lo0 = pack2(a[r0 + 0], a[r0 + 1]);
                    unsigned lo1 = pack2(a[r0 + 2], a[r0 + 3]);
                    unsigned hi0 = pack2(a[r0 + 4], a[r0 + 5]);
                    unsigned hi1 = pack2(a[r0 + 6], a[r0 + 7]);
                    asm volatile("v_permlane32_swap_b32 %0, %1" : "+v"(lo0), "+v"(hi0));
                    asm volatile("v_permlane32_swap_b32 %0, %1" : "+v"(lo1), "+v"(hi1));
                    uint4v u = {lo0, lo1, hi0, hi1};
                    bh[rt][ks] = __builtin_bit_cast(half8, u);
                }
            // keep-alive anchor: forces all 28 W(l+1) frags resident in
            // VGPRs here (prevents load-sinking into next layer; loads
            // had the whole pack phase to land -> drain ~free)
#pragma unroll
            for (int ks = 0; ks < KS; ++ks)
#pragma unroll
                for (int nt = 0; nt < NTT; ++nt)
                    asm volatile("" : "+v"(wb[ks][nt]));
        }
    }
    // acc[rt][nt] = pre-activation of layer 99 (f32) for all 128 neurons

    // ---------------- head: leaky + dot(W_out), wave-local ----------------
    float part[RT];
#pragma unroll
    for (int rt = 0; rt < RT; ++rt) {
        float s = 0.f;
#pragma unroll
        for (int nt = 0; nt < NTT; ++nt)
#pragma unroll
            for (int qd = 0; qd < 4; ++qd) {
                f32x4 w4 = *(const f32x4*)(woutp + nt * 32 + 8 * qd + 4 * g);
#pragma unroll
                for (int r = 0; r < 4; ++r) {
                    float a = acc[rt][nt][4 * qd + r];
                    float v = fmaxf(a, 0.01f * a);
                    s += v * w4[r];
                }
            }
        s += __shfl_xor(s, 32);          // combine the two k-groups (same batch row)
        part[rt] = s;
    }
    if (lane < 32) {
#pragma unroll
        for (int rt = 0; rt < RT; ++rt) {
            float tot = part[rt] + bout[0];
            out[rowbase + rt * 32 + b31] = tanhf(tot) * 4.5f + 5.5f;   // (tanh+1)/2*9+1
        }
    }
}

extern "C" void kernel_launch(void* const* d_in, const int* in_sizes, int n_in,
                              void* d_out, int out_size, void* d_ws, size_t ws_size,
                              hipStream_t stream) {
    const float* x    = (const float*)d_in[0];
    const float* Win  = (const float*)d_in[1];
    const float* bin  = (const float*)d_in[2];
    const float* Ws   = (const float*)d_in[3];
    const float* bs   = (const float*)d_in[4];
    const float* Wout = (const float*)d_in[5];
    const float* bout = (const float*)d_in[6];
    float* out = (float*)d_out;

    char* ws = (char*)d_ws;
    _Float16* wsh  = (_Float16*)ws;
    _Float16* w0sh = wsh + WSH_HALVES;
    float* bpad  = (float*)(ws + OFF_BPAD_B);
    float* woutp = (float*)(ws + OFF_WOUT_B);

    hipLaunchKernelGGL(actor_prep, dim3(NLAYERS * KS + 4 + 1), dim3(256), 0, stream,
                       Win, bin, Ws, bs, Wout, wsh, w0sh, bpad, woutp);

    const int nrows = in_sizes[0] / DIN;   // 65536
    hipLaunchKernelGGL(actor_main, dim3(nrows / ROWS), dim3(64), 0, stream,
                       x, wsh, w0sh, bpad, woutp, bout, out);
}